// Round 1
// baseline (69527.509 us; speedup 1.0000x reference)
//
#include <hip/hip_runtime.h>
#include <hip/hip_bf16.h>
#include <math.h>

#define BZ 256
#define MCN 128
#define HS 768
#define NC 7
#define LED 128
#define G4 3072

// ---------------- generic tiled GEMM: C[M,N] = A[M,K] @ B[N,K]^T (+bias[N]) (+add[M,:]) ----------------
// M = gridDim.y*64, N = gridDim.x*64, K passed (multiple of 16). All dims multiples of 64/16.
#define TBM 64
#define TBN 64
#define TBK 16

__global__ __launch_bounds__(256) void gemm_abt(
    const float* __restrict__ A, int lda,
    const float* __restrict__ B, int ldb,
    const float* __restrict__ bias,
    const float* __restrict__ add, int add_ld,
    float* __restrict__ C, int ldc, int K)
{
    __shared__ float As[TBK][TBM + 4];
    __shared__ float Bs[TBK][TBN + 4];
    const int tid = threadIdx.x;
    const int m0 = blockIdx.y * TBM;
    const int n0 = blockIdx.x * TBN;
    const int tx = tid & 15, ty = tid >> 4;
    const int lrow = tid >> 2;          // 0..63
    const int lcol = (tid & 3) * 4;     // 0,4,8,12
    float acc[4][4] = {};
    const float* Ap = A + (size_t)(m0 + lrow) * lda + lcol;
    const float* Bp = B + (size_t)(n0 + lrow) * ldb + lcol;
    for (int k0 = 0; k0 < K; k0 += TBK) {
        float4 av = *(const float4*)(Ap + k0);
        float4 bv = *(const float4*)(Bp + k0);
        As[lcol + 0][lrow] = av.x; As[lcol + 1][lrow] = av.y;
        As[lcol + 2][lrow] = av.z; As[lcol + 3][lrow] = av.w;
        Bs[lcol + 0][lrow] = bv.x; Bs[lcol + 1][lrow] = bv.y;
        Bs[lcol + 2][lrow] = bv.z; Bs[lcol + 3][lrow] = bv.w;
        __syncthreads();
        #pragma unroll
        for (int kk = 0; kk < TBK; ++kk) {
            float4 a4 = *(const float4*)&As[kk][ty * 4];
            float4 b4 = *(const float4*)&Bs[kk][tx * 4];
            float a[4] = {a4.x, a4.y, a4.z, a4.w};
            float b[4] = {b4.x, b4.y, b4.z, b4.w};
            #pragma unroll
            for (int i = 0; i < 4; ++i)
                #pragma unroll
                for (int j = 0; j < 4; ++j)
                    acc[i][j] += a[i] * b[j];
        }
        __syncthreads();
    }
    #pragma unroll
    for (int i = 0; i < 4; ++i) {
        int m = m0 + ty * 4 + i;
        float* Cr = C + (size_t)m * ldc + n0 + tx * 4;
        #pragma unroll
        for (int j = 0; j < 4; ++j) {
            float v = acc[i][j];
            if (bias) v += bias[n0 + tx * 4 + j];
            if (add)  v += add[(size_t)m * add_ld + n0 + tx * 4 + j];
            Cr[j] = v;
        }
    }
}

// ---------------- fused attention: scores -> softmax -> ctx, one block per batch row ----------------
__global__ __launch_bounds__(256) void attn_kernel(
    const float* __restrict__ q, const float* __restrict__ Kb,
    const float* __restrict__ Vb, const float* __restrict__ mask,
    float* __restrict__ ctx, float scale)
{
    __shared__ float qs[HS];
    __shared__ float sc[MCN];
    const int b = blockIdx.x, tid = threadIdx.x;
    for (int i = tid; i < HS; i += 256) qs[i] = q[(size_t)b * HS + i];
    __syncthreads();
    const int lane = tid & 63, wv = tid >> 6;
    for (int m = wv; m < MCN; m += 4) {
        const float* Kp = Kb + ((size_t)b * MCN + m) * HS;
        float s = 0.f;
        for (int k = lane; k < HS; k += 64) s += qs[k] * Kp[k];
        #pragma unroll
        for (int o = 32; o; o >>= 1) s += __shfl_down(s, o);
        if (lane == 0)
            sc[m] = s * scale + (1.0f - mask[(size_t)b * MCN + m]) * (-10000.0f);
    }
    __syncthreads();
    if (tid < 64) {  // single wave does the 128-wide softmax
        float a = sc[tid], c2 = sc[tid + 64];
        float mx = fmaxf(a, c2);
        #pragma unroll
        for (int o = 32; o; o >>= 1) mx = fmaxf(mx, __shfl_down(mx, o));
        mx = __shfl(mx, 0);
        float e0 = expf(a - mx), e1 = expf(c2 - mx);
        float ss = e0 + e1;
        #pragma unroll
        for (int o = 32; o; o >>= 1) ss += __shfl_down(ss, o);
        ss = __shfl(ss, 0);
        float inv = 1.0f / ss;
        sc[tid] = e0 * inv; sc[tid + 64] = e1 * inv;
    }
    __syncthreads();
    for (int hcol = tid; hcol < HS; hcol += 256) {
        const float* Vp = Vb + (size_t)b * MCN * HS + hcol;
        float a = 0.f;
        for (int m = 0; m < MCN; ++m) a += sc[m] * Vp[(size_t)m * HS];
        ctx[(size_t)b * HS + hcol] = a;
    }
}

// ---------------- LayerNorm over HS, one block per row ----------------
__global__ __launch_bounds__(256) void ln_kernel(
    const float* __restrict__ in, const float* __restrict__ g,
    const float* __restrict__ bb, float* __restrict__ out)
{
    __shared__ float red[4];
    const int b = blockIdx.x, tid = threadIdx.x;
    const float* row = in + (size_t)b * HS;
    float v0 = row[tid], v1 = row[tid + 256], v2 = row[tid + 512];
    float s = v0 + v1 + v2;
    #pragma unroll
    for (int o = 32; o; o >>= 1) s += __shfl_down(s, o);
    if ((tid & 63) == 0) red[tid >> 6] = s;
    __syncthreads();
    float mu = (red[0] + red[1] + red[2] + red[3]) * (1.0f / HS);
    __syncthreads();
    float d0 = v0 - mu, d1 = v1 - mu, d2 = v2 - mu;
    float qq = d0 * d0 + d1 * d1 + d2 * d2;
    #pragma unroll
    for (int o = 32; o; o >>= 1) qq += __shfl_down(qq, o);
    if ((tid & 63) == 0) red[tid >> 6] = qq;
    __syncthreads();
    float var = (red[0] + red[1] + red[2] + red[3]) * (1.0f / HS);
    float inv = 1.0f / sqrtf(var + 1e-12f);
    out[(size_t)b * HS + tid]       = d0 * inv * g[tid]       + bb[tid];
    out[(size_t)b * HS + tid + 256] = d1 * inv * g[tid + 256] + bb[tid + 256];
    out[(size_t)b * HS + tid + 512] = d2 * inv * g[tid + 512] + bb[tid + 512];
}

// ---------------- LSTM pointwise: gates[BZ,4H] -> c,h in place ----------------
__device__ __forceinline__ float sigm(float v) { return 1.0f / (1.0f + expf(-v)); }

__global__ __launch_bounds__(256) void lstm_pw(
    const float* __restrict__ gates, float* __restrict__ c, float* __restrict__ h)
{
    const int idx = blockIdx.x * 256 + threadIdx.x;       // over BZ*HS
    const int b = idx / HS, n = idx % HS;
    const float* gr = gates + (size_t)b * G4;
    float ig = sigm(gr[n]);
    float fg = sigm(gr[HS + n]);
    float gg = tanhf(gr[2 * HS + n]);
    float og = sigm(gr[3 * HS + n]);
    float cn = fg * c[idx] + ig * gg;
    c[idx] = cn;
    h[idx] = og * tanhf(cn);
}

// ---------------- pred: out[b,t,:] = h1[b]@Wout.T + bout ----------------
__global__ __launch_bounds__(64) void pred_kernel(
    const float* __restrict__ h1, const float* __restrict__ Wout,
    const float* __restrict__ bout, float* __restrict__ out, int t)
{
    const int b = blockIdx.x, c = blockIdx.y, lane = threadIdx.x;
    const float* hr = h1 + (size_t)b * HS;
    const float* wr = Wout + (size_t)c * HS;
    float s = 0.f;
    for (int k = lane; k < HS; k += 64) s += hr[k] * wr[k];
    #pragma unroll
    for (int o = 32; o; o >>= 1) s += __shfl_down(s, o);
    if (lane == 0) out[((size_t)b * MCN + t) * NC + c] = s + bout[c];
}

// ---------------- small setup kernels ----------------
__global__ void bias_comb(const float* a, const float* b, const float* c, const float* d,
                          float* o0, float* o1)
{
    int i = blockIdx.x * blockDim.x + threadIdx.x;
    if (i < G4) { o0[i] = a[i] + b[i]; o1[i] = c[i] + d[i]; }
}

// T7[c,n] = sum_d LE[c,d] * Wp[n, d]   (emb columns of Wp are [0:LED))
__global__ void t7_kernel(const float* __restrict__ LE, const float* __restrict__ Wp,
                          float* __restrict__ T7)
{
    int idx = blockIdx.x * blockDim.x + threadIdx.x;
    if (idx >= NC * HS) return;
    int c = idx / HS, n = idx % HS;
    float s = 0.f;
    for (int d = 0; d < LED; ++d) s += LE[c * LED + d] * Wp[(size_t)n * (LED + 2 * HS) + d];
    T7[idx] = s;
}

// xpre[(b*MCN+t)*HS+n] += emb contribution (teacher forcing; t==0 uses one-hot class NC-1)
__global__ void xemb_add(float* __restrict__ xpre, const float* __restrict__ tl,
                         const float* __restrict__ T7)
{
    size_t idx = (size_t)blockIdx.x * 256 + threadIdx.x;   // over BZ*MCN*HS
    size_t row = idx / HS; int n = (int)(idx % HS);
    int b = (int)(row / MCN), t = (int)(row % MCN);
    float s;
    if (t == 0) s = T7[(NC - 1) * HS + n];
    else {
        const float* lp = tl + ((size_t)b * MCN + (t - 1)) * NC;
        s = 0.f;
        #pragma unroll
        for (int c = 0; c < NC; ++c) s += lp[c] * T7[c * HS + n];
    }
    xpre[idx] += s;
}

// fallback (no xpre buffer): x[b,n] += emb contribution for a single step t
__global__ void emb_add(float* __restrict__ x, const float* __restrict__ tl,
                        const float* __restrict__ T7, int t)
{
    int idx = blockIdx.x * 256 + threadIdx.x;  // over BZ*HS
    int b = idx / HS, n = idx % HS;
    float s;
    if (t == 0) s = T7[(NC - 1) * HS + n];
    else {
        const float* lp = tl + ((size_t)b * MCN + (t - 1)) * NC;
        s = 0.f;
        #pragma unroll
        for (int c = 0; c < NC; ++c) s += lp[c] * T7[c * HS + n];
    }
    x[idx] += s;
}

extern "C" void kernel_launch(void* const* d_in, const int* in_sizes, int n_in,
                              void* d_out, int out_size, void* d_ws, size_t ws_size,
                              hipStream_t stream)
{
    (void)in_sizes; (void)n_in; (void)out_size;
    const float* cv   = (const float*)d_in[0];
    const float* mask = (const float*)d_in[1];
    const float* tl   = (const float*)d_in[2];
    const float* LE   = (const float*)d_in[3];
    const float* Wq   = (const float*)d_in[4];  const float* bq = (const float*)d_in[5];
    const float* Wk   = (const float*)d_in[6];  const float* bk = (const float*)d_in[7];
    const float* Wv   = (const float*)d_in[8];  const float* bv = (const float*)d_in[9];
    const float* Wo   = (const float*)d_in[10]; const float* bo = (const float*)d_in[11];
    const float* lng  = (const float*)d_in[12]; const float* lnb = (const float*)d_in[13];
    const float* Wp   = (const float*)d_in[14]; const float* bp = (const float*)d_in[15];
    const float* Wih0 = (const float*)d_in[16]; const float* Whh0 = (const float*)d_in[17];
    const float* bih0 = (const float*)d_in[18]; const float* bhh0 = (const float*)d_in[19];
    const float* Wih1 = (const float*)d_in[20]; const float* Whh1 = (const float*)d_in[21];
    const float* bih1 = (const float*)d_in[22]; const float* bhh1 = (const float*)d_in[23];
    const float* Wout = (const float*)d_in[24]; const float* bout = (const float*)d_in[25];
    float* out = (float*)d_out;

    const int LDP = LED + 2 * HS;  // 1664, Wp leading dim
    float* w = (float*)d_ws;
    size_t off = 0;
    auto alloc = [&](size_t n) { float* p = w + off; off += n; return p; };
    const size_t S_BH = (size_t)BZ * HS;
    const size_t S_KV = (size_t)BZ * MCN * HS;
    float* Kbuf = alloc(S_KV);
    float* Vbuf = alloc(S_KV);
    float* q    = alloc(S_BH);
    float* ctx  = alloc(S_BH);
    float* atmp = alloc(S_BH);
    float* attn = alloc(S_BH);
    float* x    = alloc(S_BH);
    float* gates = alloc((size_t)BZ * G4);
    float* h0 = alloc(S_BH);   // h0,c0,h1,c1 contiguous -> single memset
    float* c0 = alloc(S_BH);
    float* h1 = alloc(S_BH);
    float* c1 = alloc(S_BH);
    float* bc0 = alloc(G4);
    float* bc1 = alloc(G4);
    float* T7  = alloc((size_t)NC * HS);
    float* xpre = w + off;
    const bool have_xpre = ws_size >= (off + S_KV) * sizeof(float);

    hipMemsetAsync(h0, 0, 4 * S_BH * sizeof(float), stream);
    bias_comb<<<(G4 + 255) / 256, 256, 0, stream>>>(bih0, bhh0, bih1, bhh1, bc0, bc1);
    t7_kernel<<<(NC * HS + 255) / 256, 256, 0, stream>>>(LE, Wp, T7);

    dim3 blk(256);
    dim3 gKV(HS / TBN, (BZ * MCN) / TBM);   // (12, 512)
    gemm_abt<<<gKV, blk, 0, stream>>>(cv, HS, Wk, HS, bk, nullptr, 0, Kbuf, HS, HS);
    gemm_abt<<<gKV, blk, 0, stream>>>(cv, HS, Wv, HS, bv, nullptr, 0, Vbuf, HS, HS);
    if (have_xpre) {
        // xpre = cv @ WpC.T + bp   (+emb via xemb_add)
        gemm_abt<<<gKV, blk, 0, stream>>>(cv, HS, Wp + LED + HS, LDP, bp, nullptr, 0, xpre, HS, HS);
        xemb_add<<<(unsigned)(S_KV / 256), 256, 0, stream>>>(xpre, tl, T7);
    }

    const float scale = 1.0f / sqrtf((float)HS);
    dim3 g768(HS / TBN, BZ / TBM);   // (12, 4)
    dim3 gG4(G4 / TBN, BZ / TBM);    // (48, 4)

    for (int t = 0; t < MCN; ++t) {
        // q = h1 @ Wq.T + bq
        gemm_abt<<<g768, blk, 0, stream>>>(h1, HS, Wq, HS, bq, nullptr, 0, q, HS, HS);
        // scores/softmax/ctx
        attn_kernel<<<BZ, 256, 0, stream>>>(q, Kbuf, Vbuf, mask, ctx, scale);
        // atmp = ctx @ Wo.T + bo + h1 ; attn = LN(atmp)
        gemm_abt<<<g768, blk, 0, stream>>>(ctx, HS, Wo, HS, bo, h1, HS, atmp, HS, HS);
        ln_kernel<<<BZ, 256, 0, stream>>>(atmp, lng, lnb, attn);
        // x = attn @ WpA.T + xpre[t]   (xpre already contains bp + emb + cv parts)
        if (have_xpre) {
            gemm_abt<<<g768, blk, 0, stream>>>(attn, HS, Wp + LED, LDP, nullptr,
                                               xpre + (size_t)t * HS, MCN * HS, x, HS, HS);
        } else {
            gemm_abt<<<g768, blk, 0, stream>>>(attn, HS, Wp + LED, LDP, bp, nullptr, 0, x, HS, HS);
            gemm_abt<<<g768, blk, 0, stream>>>(cv + (size_t)t * HS, MCN * HS, Wp + LED + HS, LDP,
                                               nullptr, x, HS, x, HS, HS);
            emb_add<<<(unsigned)(S_BH / 256), 256, 0, stream>>>(x, tl, T7, t);
        }
        // LSTM layer 0
        gemm_abt<<<gG4, blk, 0, stream>>>(x, HS, Wih0, HS, bc0, nullptr, 0, gates, G4, HS);
        gemm_abt<<<gG4, blk, 0, stream>>>(h0, HS, Whh0, HS, nullptr, gates, G4, gates, G4, HS);
        lstm_pw<<<(unsigned)(S_BH / 256), 256, 0, stream>>>(gates, c0, h0);
        // LSTM layer 1 (input = new h0, hidden = old h1)
        gemm_abt<<<gG4, blk, 0, stream>>>(h0, HS, Wih1, HS, bc1, nullptr, 0, gates, G4, HS);
        gemm_abt<<<gG4, blk, 0, stream>>>(h1, HS, Whh1, HS, nullptr, gates, G4, gates, G4, HS);
        lstm_pw<<<(unsigned)(S_BH / 256), 256, 0, stream>>>(gates, c1, h1);
        // pred
        pred_kernel<<<dim3(BZ, NC), 64, 0, stream>>>(h1, Wout, bout, out, t);
    }
}

// Round 6
// 44136.505 us; speedup vs baseline: 1.5753x; 1.5753x over previous
//
#include <hip/hip_runtime.h>
#include <hip/hip_bf16.h>
#include <math.h>

#define BZ 256
#define MCN 128
#define HS 768
#define NC 7
#define LED 128
#define G4 3072
#define LDP (LED + 2 * HS)   // 1664

#define TBM 64
#define TBN 64
#define TBK 16

__device__ __forceinline__ ushort f2bf(float f) {
    uint x = __float_as_uint(f);
    uint r = (x + 0x7fffu + ((x >> 16) & 1u)) >> 16;   // RNE
    return (ushort)r;
}
__device__ __forceinline__ float bf2f(ushort u) {
    return __uint_as_float(((uint)u) << 16);
}

// ================= generic tiled GEMMs (fp32) =================
// C[M,N] = A[M,K] @ B[N,K]^T  (+bias[N]) (+add[M,:]) ; if Cbf != null, write bf16 instead
__global__ __launch_bounds__(256) void gemm_abt(
    const float* __restrict__ A, int lda,
    const float* __restrict__ B, int ldb,
    const float* __restrict__ bias,
    const float* __restrict__ add, long add_ld,
    float* __restrict__ C, ushort* __restrict__ Cbf, int ldc, int K)
{
    __shared__ float As[TBK][TBM + 4];
    __shared__ float Bs[TBK][TBN + 4];
    const int tid = threadIdx.x;
    const int m0 = blockIdx.y * TBM;
    const int n0 = blockIdx.x * TBN;
    const int tx = tid & 15, ty = tid >> 4;
    const int lrow = tid >> 2;
    const int lcol = (tid & 3) * 4;
    float acc[4][4] = {};
    const float* Ap = A + (size_t)(m0 + lrow) * lda + lcol;
    const float* Bp = B + (size_t)(n0 + lrow) * ldb + lcol;
    for (int k0 = 0; k0 < K; k0 += TBK) {
        float4 av = *(const float4*)(Ap + k0);
        float4 bv = *(const float4*)(Bp + k0);
        As[lcol + 0][lrow] = av.x; As[lcol + 1][lrow] = av.y;
        As[lcol + 2][lrow] = av.z; As[lcol + 3][lrow] = av.w;
        Bs[lcol + 0][lrow] = bv.x; Bs[lcol + 1][lrow] = bv.y;
        Bs[lcol + 2][lrow] = bv.z; Bs[lcol + 3][lrow] = bv.w;
        __syncthreads();
        #pragma unroll
        for (int kk = 0; kk < TBK; ++kk) {
            float4 a4 = *(const float4*)&As[kk][ty * 4];
            float4 b4 = *(const float4*)&Bs[kk][tx * 4];
            float a[4] = {a4.x, a4.y, a4.z, a4.w};
            float b[4] = {b4.x, b4.y, b4.z, b4.w};
            #pragma unroll
            for (int i = 0; i < 4; ++i)
                #pragma unroll
                for (int j = 0; j < 4; ++j)
                    acc[i][j] += a[i] * b[j];
        }
        __syncthreads();
    }
    #pragma unroll
    for (int i = 0; i < 4; ++i) {
        int m = m0 + ty * 4 + i;
        #pragma unroll
        for (int j = 0; j < 4; ++j) {
            float v = acc[i][j];
            if (bias) v += bias[n0 + tx * 4 + j];
            if (add)  v += add[(size_t)m * add_ld + n0 + tx * 4 + j];
            if (Cbf) Cbf[(size_t)m * ldc + n0 + tx * 4 + j] = f2bf(v);
            else     C  [(size_t)m * ldc + n0 + tx * 4 + j] = v;
        }
    }
}

// C[M,N] = A[M,K] @ B[K,N]   (B row-major over N, ld=ldb)
__global__ __launch_bounds__(256) void gemm_ab(
    const float* __restrict__ A, int lda,
    const float* __restrict__ B, int ldb,
    float* __restrict__ C, int ldc, int K)
{
    __shared__ float As[TBK][TBM + 4];
    __shared__ float Bs[TBK][TBN + 4];
    const int tid = threadIdx.x;
    const int m0 = blockIdx.y * TBM, n0 = blockIdx.x * TBN;
    const int tx = tid & 15, ty = tid >> 4;
    float acc[4][4] = {};
    for (int k0 = 0; k0 < K; k0 += TBK) {
        #pragma unroll
        for (int i = 0; i < 4; ++i) {
            int idx = tid + i * 256;
            int r = idx >> 4, kk = idx & 15;
            As[kk][r] = A[(size_t)(m0 + r) * lda + k0 + kk];
        }
        #pragma unroll
        for (int i = 0; i < 4; ++i) {
            int idx = tid + i * 256;
            int kk = idx >> 6, cc = idx & 63;
            Bs[kk][cc] = B[(size_t)(k0 + kk) * ldb + n0 + cc];
        }
        __syncthreads();
        #pragma unroll
        for (int kk = 0; kk < TBK; ++kk) {
            float4 a4 = *(const float4*)&As[kk][ty * 4];
            float4 b4 = *(const float4*)&Bs[kk][tx * 4];
            float a[4] = {a4.x, a4.y, a4.z, a4.w};
            float b[4] = {b4.x, b4.y, b4.z, b4.w};
            #pragma unroll
            for (int i = 0; i < 4; ++i)
                #pragma unroll
                for (int j = 0; j < 4; ++j)
                    acc[i][j] += a[i] * b[j];
        }
        __syncthreads();
    }
    #pragma unroll
    for (int i = 0; i < 4; ++i) {
        float* Cr = C + (size_t)(m0 + ty * 4 + i) * ldc + n0 + tx * 4;
        #pragma unroll
        for (int j = 0; j < 4; ++j) Cr[j] = acc[i][j];
    }
}

// C[M,N] = alpha * A^T @ B : A[K,M], B[K,N]
__global__ __launch_bounds__(256) void gemm_atb(
    const float* __restrict__ A, int lda,
    const float* __restrict__ B, int ldb,
    float* __restrict__ C, int ldc, int K, float alpha)
{
    __shared__ float As[TBK][TBM + 4];
    __shared__ float Bs[TBK][TBN + 4];
    const int tid = threadIdx.x;
    const int m0 = blockIdx.y * TBM, n0 = blockIdx.x * TBN;
    const int tx = tid & 15, ty = tid >> 4;
    float acc[4][4] = {};
    for (int k0 = 0; k0 < K; k0 += TBK) {
        #pragma unroll
        for (int i = 0; i < 4; ++i) {
            int idx = tid + i * 256;
            int kk = idx >> 6, r = idx & 63;
            As[kk][r] = A[(size_t)(k0 + kk) * lda + m0 + r];
            Bs[kk][r] = B[(size_t)(k0 + kk) * ldb + n0 + r];
        }
        __syncthreads();
        #pragma unroll
        for (int kk = 0; kk < TBK; ++kk) {
            float4 a4 = *(const float4*)&As[kk][ty * 4];
            float4 b4 = *(const float4*)&Bs[kk][tx * 4];
            float a[4] = {a4.x, a4.y, a4.z, a4.w};
            float b[4] = {b4.x, b4.y, b4.z, b4.w};
            #pragma unroll
            for (int i = 0; i < 4; ++i)
                #pragma unroll
                for (int j = 0; j < 4; ++j)
                    acc[i][j] += a[i] * b[j];
        }
        __syncthreads();
    }
    #pragma unroll
    for (int i = 0; i < 4; ++i) {
        float* Cr = C + (size_t)(m0 + ty * 4 + i) * ldc + n0 + tx * 4;
        #pragma unroll
        for (int j = 0; j < 4; ++j) Cr[j] = alpha * acc[i][j];
    }
}

// ================= fused per-step attention (bf16 K'/V') =================
// scores = h1@K'^T + cmask -> softmax -> o = probs@V' + bo + h1 -> LN -> attn
// also writes pred for step t-1 from h1
__global__ __launch_bounds__(768) void attn_step(
    const float* __restrict__ h1, const ushort* __restrict__ Kp,
    const ushort* __restrict__ Vp, const float* __restrict__ cmask,
    const float* __restrict__ lng, const float* __restrict__ lnb,
    const float* __restrict__ bo,
    const float* __restrict__ Wout, const float* __restrict__ bout,
    float* __restrict__ out, float* __restrict__ attn_out, int t)
{
    __shared__ float hs[HS];
    __shared__ float sc[MCN];
    __shared__ float red[12];
    const int b = blockIdx.x, tid = threadIdx.x;
    const int lane = tid & 63, wv = tid >> 6;   // 12 waves
    hs[tid] = h1[(size_t)b * HS + tid];
    __syncthreads();
    if (t > 0 && wv < NC) {
        const float* wr = Wout + (size_t)wv * HS;
        float s = 0.f;
        #pragma unroll
        for (int k = lane; k < HS; k += 64) s += hs[k] * wr[k];
        #pragma unroll
        for (int o = 32; o; o >>= 1) s += __shfl_down(s, o);
        if (lane == 0) out[((size_t)b * MCN + (t - 1)) * NC + wv] = s + bout[wv];
    }
    const ushort* Kb = Kp + (size_t)b * MCN * HS;
    for (int m = wv; m < MCN; m += 12) {
        const ushort* kr = Kb + (size_t)m * HS;
        float s = 0.f;
        #pragma unroll
        for (int k = lane * 2; k < HS; k += 128) {
            uint v = *(const uint*)(kr + k);
            s += hs[k] * bf2f((ushort)(v & 0xffffu))
               + hs[k + 1] * bf2f((ushort)(v >> 16));
        }
        #pragma unroll
        for (int o = 32; o; o >>= 1) s += __shfl_down(s, o);
        if (lane == 0) sc[m] = s + cmask[(size_t)b * MCN + m];
    }
    __syncthreads();
    if (tid < 64) {
        float a = sc[tid], c2 = sc[tid + 64];
        float mx = fmaxf(a, c2);
        #pragma unroll
        for (int o = 32; o; o >>= 1) mx = fmaxf(mx, __shfl_down(mx, o));
        mx = __shfl(mx, 0);
        float e0 = expf(a - mx), e1 = expf(c2 - mx);
        float ss = e0 + e1;
        #pragma unroll
        for (int o = 32; o; o >>= 1) ss += __shfl_down(ss, o);
        ss = __shfl(ss, 0);
        float inv = 1.0f / ss;
        sc[tid] = e0 * inv; sc[tid + 64] = e1 * inv;
    }
    __syncthreads();
    const int n = tid;
    const ushort* vp = Vp + (size_t)b * MCN * HS + n;
    float a = 0.f;
    #pragma unroll 8
    for (int m = 0; m < MCN; ++m) a += sc[m] * bf2f(vp[(size_t)m * HS]);
    a += bo[n] + hs[n];
    float lsum = a;
    #pragma unroll
    for (int o = 32; o; o >>= 1) lsum += __shfl_down(lsum, o);
    if (lane == 0) red[wv] = lsum;
    __syncthreads();
    float mu = 0.f;
    #pragma unroll
    for (int i = 0; i < 12; ++i) mu += red[i];
    mu *= (1.0f / HS);
    __syncthreads();
    float d = a - mu;
    float qq = d * d;
    #pragma unroll
    for (int o = 32; o; o >>= 1) qq += __shfl_down(qq, o);
    if (lane == 0) red[wv] = qq;
    __syncthreads();
    float var = 0.f;
    #pragma unroll
    for (int i = 0; i < 12; ++i) var += red[i];
    var *= (1.0f / HS);
    float inv = 1.0f / sqrtf(var + 1e-12f);
    attn_out[(size_t)b * HS + n] = d * inv * lng[n] + lnb[n];
}

// ================= fused LSTM step: gates GEMM (concat K) + pointwise =================
// gates = A1@B1^T + A2@B2^T + pre ; i,f,g,o -> c,h
__global__ __launch_bounds__(256) void lstm_step(
    const float* __restrict__ A1, const float* __restrict__ B1,
    const float* __restrict__ A2, const float* __restrict__ B2,
    const float* __restrict__ pre, size_t pre_stride,
    float* __restrict__ cbuf, float* __restrict__ hout)
{
    __shared__ float As[TBK][36];
    __shared__ float Bs[4][TBK][36];
    const int tid = threadIdx.x;
    const int n0 = blockIdx.x * 32;
    const int b0 = blockIdx.y * 32;
    const int rb = tid >> 5;     // 0..7
    const int nn = tid & 31;
    float acc[4][4] = {};
    #pragma unroll
    for (int ph = 0; ph < 2; ++ph) {
        const float* A = ph ? A2 : A1;
        const float* B = ph ? B2 : B1;
        for (int k0 = 0; k0 < HS; k0 += TBK) {
            #pragma unroll
            for (int i = 0; i < 2; ++i) {
                int idx = tid + i * 256;
                int r = idx >> 4, kk = idx & 15;
                As[kk][r] = A[(size_t)(b0 + r) * HS + k0 + kk];
            }
            #pragma unroll
            for (int i = 0; i < 8; ++i) {
                int idx = tid + i * 256;
                int s = idx >> 9, rem = idx & 511;
                int r = rem >> 4, kk = rem & 15;
                Bs[s][kk][r] = B[(size_t)(s * HS + n0 + r) * HS + k0 + kk];
            }
            __syncthreads();
            #pragma unroll
            for (int kk = 0; kk < TBK; ++kk) {
                float b0v = Bs[0][kk][nn], b1v = Bs[1][kk][nn];
                float b2v = Bs[2][kk][nn], b3v = Bs[3][kk][nn];
                #pragma unroll
                for (int k = 0; k < 4; ++k) {
                    float a = As[kk][rb + 8 * k];
                    acc[k][0] += a * b0v; acc[k][1] += a * b1v;
                    acc[k][2] += a * b2v; acc[k][3] += a * b3v;
                }
            }
            __syncthreads();
        }
    }
    #pragma unroll
    for (int k = 0; k < 4; ++k) {
        int b = b0 + rb + 8 * k;
        int n = n0 + nn;
        const float* pr = pre + (size_t)b * pre_stride;
        float ig = acc[k][0] + pr[n];
        float fg = acc[k][1] + pr[HS + n];
        float gg = acc[k][2] + pr[2 * HS + n];
        float og = acc[k][3] + pr[3 * HS + n];
        ig = 1.f / (1.f + expf(-ig));
        fg = 1.f / (1.f + expf(-fg));
        og = 1.f / (1.f + expf(-og));
        gg = tanhf(gg);
        size_t idx = (size_t)b * HS + n;
        float cn = fg * cbuf[idx] + ig * gg;
        cbuf[idx] = cn;
        hout[idx] = og * tanhf(cn);
    }
}

// ================= small setup / fold kernels =================
__global__ void bias_comb(const float* a, const float* b, const float* c, const float* d,
                          float* o0, float* o1)
{
    int i = blockIdx.x * blockDim.x + threadIdx.x;
    if (i < G4) { o0[i] = a[i] + b[i]; o1[i] = c[i] + d[i]; }
}

__global__ void t7_kernel(const float* __restrict__ LE, const float* __restrict__ Wp,
                          float* __restrict__ T7)
{
    int idx = blockIdx.x * blockDim.x + threadIdx.x;
    if (idx >= NC * HS) return;
    int c = idx / HS, n = idx % HS;
    float s = 0.f;
    for (int d = 0; d < LED; ++d) s += LE[c * LED + d] * Wp[(size_t)n * LDP + d];
    T7[idx] = s;
}

// bkq[j] = scale*(bk@Wq[:,j]) ; bvo[j] = bv@Wo[j,:] ; kqv[j] = scale*(bq@Wk[:,j]) ; kqv[HS] = scale*bq.bk
__global__ void fold_vecs(const float* __restrict__ Wq, const float* __restrict__ Wk,
                          const float* __restrict__ Wo,
                          const float* __restrict__ bq, const float* __restrict__ bk,
                          const float* __restrict__ bv,
                          float* __restrict__ bkq, float* __restrict__ bvo,
                          float* __restrict__ kqv, float scale)
{
    int j = blockIdx.x * 256 + threadIdx.x;
    if (j < HS) {
        float s1 = 0.f, s2 = 0.f, s3 = 0.f;
        for (int i = 0; i < HS; ++i) {
            s1 += bk[i] * Wq[(size_t)i * HS + j];
            s2 += bv[i] * Wo[(size_t)j * HS + i];
            s3 += bq[i] * Wk[(size_t)i * HS + j];
        }
        bkq[j] = s1 * scale; bvo[j] = s2; kqv[j] = s3 * scale;
    } else if (j == HS) {
        float s = 0.f;
        for (int i = 0; i < HS; ++i) s += bq[i] * bk[i];
        kqv[HS] = s * scale;
    }
}

// cmask[b,m] = cv[b,m]@(scale-folded kqv) + scale*bq.bk + (1-mask)*-1e4
__global__ __launch_bounds__(256) void cmask_kernel(
    const float* __restrict__ cv, const float* __restrict__ mask,
    const float* __restrict__ kqv, float* __restrict__ cm)
{
    int row = blockIdx.x * 4 + (threadIdx.x >> 6);
    int lane = threadIdx.x & 63;
    const float* r = cv + (size_t)row * HS;
    float s = 0.f;
    #pragma unroll
    for (int k = lane; k < HS; k += 64) s += r[k] * kqv[k];
    #pragma unroll
    for (int o = 32; o; o >>= 1) s += __shfl_down(s, o);
    if (lane == 0)
        cm[row] = s + kqv[HS] + (1.0f - mask[row]) * (-10000.0f);
}

// T7g[c,g] = T7[c]@Wih0[g] ; bp0[g] = bp@Wih0[g] + bih0[g] + bhh0[g]
__global__ void t7g_bp0(const float* __restrict__ T7, const float* __restrict__ Wih0,
                        const float* __restrict__ bp, const float* __restrict__ bih0,
                        const float* __restrict__ bhh0,
                        float* __restrict__ T7g, float* __restrict__ bp0)
{
    int g = blockIdx.x * 256 + threadIdx.x;
    if (g >= G4) return;
    float acc[NC] = {};
    float ab = 0.f;
    const float* wr = Wih0 + (size_t)g * HS;
    for (int n = 0; n < HS; ++n) {
        float w = wr[n];
        ab += bp[n] * w;
        #pragma unroll
        for (int c = 0; c < NC; ++c) acc[c] += T7[c * HS + n] * w;
    }
    #pragma unroll
    for (int c = 0; c < NC; ++c) T7g[c * G4 + g] = acc[c];
    bp0[g] = ab + bih0[g] + bhh0[g];
}

// gpre0[row,g] += bp0[g] + emb-through-Wih0 ; grid (12, BZ*MCN)
__global__ void gemb(float* __restrict__ gpre, const float* __restrict__ tl,
                     const float* __restrict__ T7g, const float* __restrict__ bp0)
{
    int g = blockIdx.x * 256 + threadIdx.x;
    size_t row = blockIdx.y;
    int t = (int)(row & (MCN - 1));
    float s = bp0[g];
    if (t == 0) s += T7g[(NC - 1) * G4 + g];
    else {
        const float* lp = tl + (row - 1) * NC;
        #pragma unroll
        for (int c = 0; c < NC; ++c) s += lp[c] * T7g[c * G4 + g];
    }
    gpre[row * G4 + g] += s;
}

// xpre[row,n] += emb ; grid (3, BZ*MCN)
__global__ void xemb_add(float* __restrict__ xpre, const float* __restrict__ tl,
                         const float* __restrict__ T7)
{
    int n = blockIdx.x * 256 + threadIdx.x;
    size_t row = blockIdx.y;
    int t = (int)(row & (MCN - 1));
    float s;
    if (t == 0) s = T7[(NC - 1) * HS + n];
    else {
        const float* lp = tl + (row - 1) * NC;
        s = 0.f;
        #pragma unroll
        for (int c = 0; c < NC; ++c) s += lp[c] * T7[c * HS + n];
    }
    xpre[row * HS + n] += s;
}

// tier-C per-step emb add ; grid (3, BZ)
__global__ void emb_add(float* __restrict__ x, const float* __restrict__ tl,
                        const float* __restrict__ T7, int t)
{
    int n = blockIdx.x * 256 + threadIdx.x;
    int b = blockIdx.y;
    float s;
    if (t == 0) s = T7[(NC - 1) * HS + n];
    else {
        const float* lp = tl + ((size_t)b * MCN + (t - 1)) * NC;
        s = 0.f;
        #pragma unroll
        for (int c = 0; c < NC; ++c) s += lp[c] * T7[c * HS + n];
    }
    x[(size_t)b * HS + n] += s;
}

__global__ __launch_bounds__(64) void pred_kernel(
    const float* __restrict__ h1, const float* __restrict__ Wout,
    const float* __restrict__ bout, float* __restrict__ out, int t)
{
    const int b = blockIdx.x, c = blockIdx.y, lane = threadIdx.x;
    const float* hr = h1 + (size_t)b * HS;
    const float* wr = Wout + (size_t)c * HS;
    float s = 0.f;
    #pragma unroll
    for (int k = lane; k < HS; k += 64) s += hr[k] * wr[k];
    #pragma unroll
    for (int o = 32; o; o >>= 1) s += __shfl_down(s, o);
    if (lane == 0) out[((size_t)b * MCN + t) * NC + c] = s + bout[c];
}

// ================= host =================
extern "C" void kernel_launch(void* const* d_in, const int* in_sizes, int n_in,
                              void* d_out, int out_size, void* d_ws, size_t ws_size,
                              hipStream_t stream)
{
    (void)in_sizes; (void)n_in; (void)out_size;
    const float* cv   = (const float*)d_in[0];
    const float* mask = (const float*)d_in[1];
    const float* tl   = (const float*)d_in[2];
    const float* LE   = (const float*)d_in[3];
    const float* Wq   = (const float*)d_in[4];  const float* bq  = (const float*)d_in[5];
    const float* Wk   = (const float*)d_in[6];  const float* bk  = (const float*)d_in[7];
    const float* Wv   = (const float*)d_in[8];  const float* bv  = (const float*)d_in[9];
    const float* Wo   = (const float*)d_in[10]; const float* bo  = (const float*)d_in[11];
    const float* lng  = (const float*)d_in[12]; const float* lnb = (const float*)d_in[13];
    const float* Wp   = (const float*)d_in[14]; const float* bp  = (const float*)d_in[15];
    const float* Wih0 = (const float*)d_in[16]; const float* Whh0 = (const float*)d_in[17];
    const float* bih0 = (const float*)d_in[18]; const float* bhh0 = (const float*)d_in[19];
    const float* Wih1 = (const float*)d_in[20]; const float* Whh1 = (const float*)d_in[21];
    const float* bih1 = (const float*)d_in[22]; const float* bhh1 = (const float*)d_in[23];
    const float* Wout = (const float*)d_in[24]; const float* bout = (const float*)d_in[25];
    float* out = (float*)d_out;

    const size_t S_BH = (size_t)BZ * HS;
    const size_t S_KV = (size_t)BZ * MCN * HS;    // 25.17M elements
    const size_t S_G  = (size_t)BZ * MCN * G4;

    float* w = (float*)d_ws;
    size_t off = 0;
    auto alloc = [&](size_t n) { off = (off + 3) & ~(size_t)3; float* p = w + off; off += n; return p; };
    ushort* Kbf  = (ushort*)alloc(S_KV / 2);      // bf16 K'
    ushort* Vbf  = (ushort*)alloc(S_KV / 2);      // bf16 V'
    float* cmask = alloc((size_t)BZ * MCN);
    float* attn  = alloc(S_BH);
    float* x     = alloc(S_BH);
    float* c0    = alloc(S_BH);   // c0,c1,h0a,h1a contiguous -> one memset
    float* c1    = alloc(S_BH);
    float* h0a   = alloc(S_BH);
    float* h1a   = alloc(S_BH);
    float* h0b   = alloc(S_BH);
    float* h1b   = alloc(S_BH);
    float* WkqT  = alloc((size_t)HS * HS);
    float* WvoT  = alloc((size_t)HS * HS);
    float* W0x   = alloc((size_t)G4 * HS);
    float* T7    = alloc((size_t)NC * HS);
    float* bc0   = alloc(G4);
    float* bc1   = alloc(G4);
    float* bkq   = alloc(HS);
    float* bvo   = alloc(HS);
    float* kqv   = alloc(HS + 1);
    off = (off + 3) & ~(size_t)3;
    const size_t base_end = off;
    // tier-full extras
    float* W0c   = w + base_end;
    float* T7g   = W0c + (size_t)G4 * HS;
    float* bp0   = T7g + (size_t)NC * G4;
    float* gpre0 = bp0 + G4;
    const size_t full_end = (size_t)(gpre0 - w) + S_G;
    // tier-A extra
    float* xpre  = w + base_end;
    const size_t A_end = base_end + S_KV;

    const int tier = (ws_size >= full_end * sizeof(float)) ? 2
                   : (ws_size >= A_end * sizeof(float))    ? 1 : 0;

    const float scale = 1.0f / sqrtf((float)HS);

    hipMemsetAsync(c0, 0, 4 * S_BH * sizeof(float), stream);
    bias_comb<<<(G4 + 255) / 256, 256, 0, stream>>>(bih0, bhh0, bih1, bhh1, bc0, bc1);
    t7_kernel<<<(NC * HS + 255) / 256, 256, 0, stream>>>(LE, Wp, T7);
    // weight folds (scale folded into score path: WkqT, bkq, kqv, bq.bk)
    gemm_atb<<<dim3(12, 12), 256, 0, stream>>>(Wq, HS, Wk, HS, WkqT, HS, HS, scale);
    gemm_ab <<<dim3(12, 12), 256, 0, stream>>>(Wo, HS, Wv, HS, WvoT, HS, HS);
    gemm_ab <<<dim3(12, 48), 256, 0, stream>>>(Wih0, HS, Wp + LED, LDP, W0x, HS, HS);
    fold_vecs<<<4, 256, 0, stream>>>(Wq, Wk, Wo, bq, bk, bv, bkq, bvo, kqv, scale);
    cmask_kernel<<<(BZ * MCN) / 4, 256, 0, stream>>>(cv, mask, kqv, cmask);
    // big precompute GEMMs (K'/V' written directly as bf16 via fused epilogue)
    dim3 blk(256);
    gemm_abt<<<dim3(12, (BZ * MCN) / TBM), blk, 0, stream>>>(cv, HS, WkqT, HS, bkq, nullptr, 0,
                                                             nullptr, Kbf, HS, HS);
    gemm_abt<<<dim3(12, (BZ * MCN) / TBM), blk, 0, stream>>>(cv, HS, WvoT, HS, bvo, nullptr, 0,
                                                             nullptr, Vbf, HS, HS);
    if (tier == 2) {
        gemm_ab<<<dim3(12, 48), 256, 0, stream>>>(Wih0, HS, Wp + LED + HS, LDP, W0c, HS, HS);
        t7g_bp0<<<12, 256, 0, stream>>>(T7, Wih0, bp, bih0, bhh0, T7g, bp0);
        gemm_abt<<<dim3(48, (BZ * MCN) / TBM), blk, 0, stream>>>(cv, HS, W0c, HS, nullptr, nullptr, 0,
                                                                 gpre0, nullptr, G4, HS);
        gemb<<<dim3(12, BZ * MCN), 256, 0, stream>>>(gpre0, tl, T7g, bp0);
    } else if (tier == 1) {
        gemm_abt<<<dim3(12, (BZ * MCN) / TBM), blk, 0, stream>>>(cv, HS, Wp + LED + HS, LDP, bp,
                                                                 nullptr, 0, xpre, nullptr, HS, HS);
        xemb_add<<<dim3(3, BZ * MCN), 256, 0, stream>>>(xpre, tl, T7);
    }

    for (int t = 0; t < MCN; ++t) {
        const float* h0r = (t & 1) ? h0b : h0a;  float* h0w = (t & 1) ? h0a : h0b;
        const float* h1r = (t & 1) ? h1b : h1a;  float* h1w = (t & 1) ? h1a : h1b;
        attn_step<<<BZ, 768, 0, stream>>>(h1r, Kbf, Vbf, cmask, lng, lnb, bo,
                                          Wout, bout, out, attn, t);
        if (tier == 2) {
            lstm_step<<<dim3(24, 8), 256, 0, stream>>>(attn, W0x, h0r, Whh0,
                                                       gpre0 + (size_t)t * G4, (size_t)MCN * G4,
                                                       c0, h0w);
        } else {
            if (tier == 1) {
                gemm_abt<<<dim3(12, 4), blk, 0, stream>>>(attn, HS, Wp + LED, LDP, nullptr,
                                                          xpre + (size_t)t * HS, (size_t)MCN * HS,
                                                          x, nullptr, HS, HS);
            } else {
                gemm_abt<<<dim3(12, 4), blk, 0, stream>>>(attn, HS, Wp + LED, LDP, bp,
                                                          nullptr, 0, x, nullptr, HS, HS);
                gemm_abt<<<dim3(12, 4), blk, 0, stream>>>(cv + (size_t)t * HS, MCN * HS,
                                                          Wp + LED + HS, LDP, nullptr,
                                                          x, HS, x, nullptr, HS, HS);
                emb_add<<<dim3(3, BZ), 256, 0, stream>>>(x, tl, T7, t);
            }
            lstm_step<<<dim3(24, 8), 256, 0, stream>>>(x, Wih0, h0r, Whh0, bc0, 0, c0, h0w);
        }
        lstm_step<<<dim3(24, 8), 256, 0, stream>>>(h0w, Wih1, h1r, Whh1, bc1, 0, c1, h1w);
    }
    pred_kernel<<<dim3(BZ, NC), 64, 0, stream>>>(h1a, Wout, bout, out, MCN - 1);
}